// Round 10
// baseline (124.406 us; speedup 1.0000x reference)
//
#include <hip/hip_runtime.h>
#include <hip/hip_bf16.h>
#include <stdint.h>

// ---------------- problem constants ----------------
#define PDIM   1024
#define HEADS  16
#define DHEAD  64
#define BATCH  2
#define SEQ    2048
#define ROWS   (BATCH*SEQ)     // 4096
#define NBH    (BATCH*HEADS)   // 32

typedef __attribute__((ext_vector_type(8))) short s8v;    // 8 x bf16 (4 VGPR)
typedef __attribute__((ext_vector_type(4))) float f32x4;  // MFMA accumulator
typedef unsigned short ushort_t;
typedef unsigned int   uint32;

// Q pre-scale: DIM_HEAD^-0.5 * log2(e)  (softmax done in exp2 units)
#define QSCALE 0.18033688011112042f
// fixed softmax bias (log2 units): p = exp2(s - MFIX); cancels in num/denom
#define MFIX 12.0f

// ---------------- helpers ----------------
__device__ __forceinline__ ushort_t f2bf(float x){
  union { float f; uint32 u; } v; v.f = x;
  uint32 r = v.u + 0x7FFFu + ((v.u >> 16) & 1u);   // RTN-even
  return (ushort_t)(r >> 16);
}
__device__ __forceinline__ uint32 cvt_pk_bf16(float lo, float hi){
  uint32 r;
  asm("v_cvt_pk_bf16_f32 %0, %1, %2" : "=v"(r) : "v"(lo), "v"(hi));
  return r;   // bf16(lo) in [15:0], bf16(hi) in [31:16]
}

typedef const __attribute__((address_space(1))) void* gas_ptr;
typedef __attribute__((address_space(3))) void*       las_ptr;
__device__ __forceinline__ void g2l16(const void* g, void* l){
  // dest = wave-uniform LDS base; HW adds lane*16
  __builtin_amdgcn_global_load_lds((gas_ptr)g, (las_ptr)l, 16, 0, 0);
}

// ---------------- fused prep: x cvt + w_qkv tcvt + w_out tcvt ----------------
__global__ __launch_bounds__(256) void k_prep(
    const float* __restrict__ x, const float* __restrict__ w_qkv,
    const float* __restrict__ w_out,
    ushort_t* __restrict__ Xh, ushort_t* __restrict__ Wqt_h,
    ushort_t* __restrict__ Wot_h){
  __shared__ float tile[64][65];
  const int bid = blockIdx.x;
  if (bid < 4096){
    int i = bid * 256 + threadIdx.x;
    float4 v = reinterpret_cast<const float4*>(x)[i];
    reinterpret_cast<ushort4*>(Xh)[i] =
        make_ushort4(f2bf(v.x), f2bf(v.y), f2bf(v.z), f2bf(v.w));
    return;
  }
  const float* src; ushort_t* dst; int R, C, cb, rb;
  if (bid < 4864){
    int t = bid - 4096; src = w_qkv; dst = Wqt_h; R = 1024; C = 3072;
    cb = (t % 48) * 64; rb = (t / 48) * 64;
  } else {
    int t = bid - 4864; src = w_out; dst = Wot_h; R = 1024; C = 1024;
    cb = (t % 16) * 64; rb = (t / 16) * 64;
  }
  int t = threadIdx.x;
  int lw = t >> 6, lc = t & 63;
#pragma unroll
  for (int i = 0; i < 16; i++){
    int r = i * 4 + lw;
    tile[r][lc] = src[(size_t)(rb + r) * C + cb + lc];
  }
  __syncthreads();
#pragma unroll
  for (int i = 0; i < 16; i++){
    int c = i * 4 + lw;
    dst[(size_t)(cb + c) * R + rb + lc] = f2bf(tile[lc][c]);
  }
}

// ---------------- GEMM core (128x128 tile, BK=64, 4 waves, dbuf + swizzle) ----------------
#define GBM 128
#define GBN 128
#define GBK 64

// ---------------- QKV projection GEMM, fused per-head epilogue ----------------
__global__ __launch_bounds__(256, 2) void k_gemm_qkv(
    const ushort_t* __restrict__ Xh, const ushort_t* __restrict__ Wqt_h,
    ushort_t* __restrict__ Qh, ushort_t* __restrict__ Kh, ushort_t* __restrict__ Vth){
  __shared__ __align__(16) ushort_t Asm[2][GBM * GBK];
  __shared__ __align__(16) ushort_t Bsm[2][GBM * GBK];
  const int tid  = threadIdx.x;
  const int wave = tid >> 6, lane = tid & 63;
  const int mb = blockIdx.y * GBM, nb = blockIdx.x * GBN;
  const int wr = wave >> 1, wc = wave & 1;
  const int l15 = lane & 15, l4 = lane >> 4;
  const int rsub = lane >> 3;
  const int schunk = ((lane & 7) ^ rsub) * 8;  // source-swizzled chunk
  f32x4 acc[4][4] = {};

  auto stage = [&](int buf, int kb){
    int k0 = kb * GBK;
#pragma unroll
    for (int i = 0; i < 4; i++){
      int row = (i * 4 + wave) * 8 + rsub;
      g2l16(Xh    + (size_t)(mb + row) * 1024 + k0 + schunk, &Asm[buf][(i * 4 + wave) * 512]);
      g2l16(Wqt_h + (size_t)(nb + row) * 1024 + k0 + schunk, &Bsm[buf][(i * 4 + wave) * 512]);
    }
  };

  stage(0, 0);

  for (int kb = 0; kb < 16; kb++){
    const int cur = kb & 1;
    if (kb < 15){
      stage(cur ^ 1, kb + 1);
      asm volatile("s_waitcnt vmcnt(8)" ::: "memory");
    } else {
      asm volatile("s_waitcnt vmcnt(0)" ::: "memory");
    }
    __builtin_amdgcn_s_barrier();
    __builtin_amdgcn_s_setprio(1);
#pragma unroll
    for (int ks = 0; ks < 2; ks++){
      s8v af[4], bfr[4];
#pragma unroll
      for (int f = 0; f < 4; f++){
        int ch = (((ks * 4 + l4) ^ (l15 & 7)) << 3);
        af[f]  = *reinterpret_cast<const s8v*>(&Asm[cur][(wr * 64 + f * 16 + l15) * 64 + ch]);
        bfr[f] = *reinterpret_cast<const s8v*>(&Bsm[cur][(wc * 64 + f * 16 + l15) * 64 + ch]);
      }
#pragma unroll
      for (int fr = 0; fr < 4; fr++)
#pragma unroll
        for (int fc = 0; fc < 4; fc++)
          acc[fr][fc] = __builtin_amdgcn_mfma_f32_16x16x32_bf16(af[fr], bfr[fc], acc[fr][fc], 0, 0, 0);
    }
    __builtin_amdgcn_s_setprio(0);
    __builtin_amdgcn_s_barrier();
  }

  // fused epilogue: cols [nb,nb+128) all in one part (1024 % 128 == 0)
  const int pnum = nb >> 10;
#pragma unroll
  for (int fr = 0; fr < 4; fr++){
    int row  = mb + wr * 64 + fr * 16 + l4 * 4;
    int b    = row >> 11;
    int nseq = row & 2047;
#pragma unroll
    for (int fc = 0; fc < 4; fc++){
      int col = nb + wc * 64 + fc * 16 + l15;
      int rem = col & 1023;
      int h = rem >> 6, d = rem & 63;
      int bh = b * 16 + h;
      if (pnum == 0){          // Q: scale, hi only
        size_t base = ((size_t)bh * SEQ + nseq) * 64 + d;
#pragma unroll
        for (int r = 0; r < 4; r++)
          Qh[base + (size_t)r * 64] = f2bf(acc[fr][fc][r] * QSCALE);
      } else if (pnum == 1){   // K: hi only
        size_t base = ((size_t)bh * SEQ + nseq) * 64 + d;
#pragma unroll
        for (int r = 0; r < 4; r++)
          Kh[base + (size_t)r * 64] = f2bf(acc[fr][fc][r]);
      } else {                 // V: transposed [bh][d][SEQ]
        size_t base = ((size_t)bh * 64 + d) * SEQ + nseq;
        *reinterpret_cast<ushort4*>(&Vth[base]) =
            make_ushort4(f2bf(acc[fr][fc][0]), f2bf(acc[fr][fc][1]),
                         f2bf(acc[fr][fc][2]), f2bf(acc[fr][fc][3]));
      }
    }
  }
}

// ---------------- out-projection GEMM (plain bf16, dbuf + swizzle) ----------------
__global__ __launch_bounds__(256, 2) void k_gemm_out(
    const ushort_t* __restrict__ Ah, const ushort_t* __restrict__ Bth,
    float* __restrict__ C, const float* __restrict__ bias){
  __shared__ __align__(16) ushort_t Asm[2][GBM * GBK];
  __shared__ __align__(16) ushort_t Bsm[2][GBM * GBK];
  const int tid  = threadIdx.x;
  const int wave = tid >> 6, lane = tid & 63;
  const int mb = blockIdx.y * GBM, nb = blockIdx.x * GBN;
  const int wr = wave >> 1, wc = wave & 1;
  const int l15 = lane & 15, l4 = lane >> 4;
  const int rsub = lane >> 3;
  const int schunk = ((lane & 7) ^ rsub) * 8;
  f32x4 acc[4][4] = {};

  auto stage = [&](int buf, int kb){
    int k0 = kb * GBK;
#pragma unroll
    for (int i = 0; i < 4; i++){
      int row = (i * 4 + wave) * 8 + rsub;
      g2l16(Ah  + (size_t)(mb + row) * 1024 + k0 + schunk, &Asm[buf][(i * 4 + wave) * 512]);
      g2l16(Bth + (size_t)(nb + row) * 1024 + k0 + schunk, &Bsm[buf][(i * 4 + wave) * 512]);
    }
  };

  stage(0, 0);

  for (int kb = 0; kb < 16; kb++){
    const int cur = kb & 1;
    if (kb < 15){
      stage(cur ^ 1, kb + 1);
      asm volatile("s_waitcnt vmcnt(8)" ::: "memory");
    } else {
      asm volatile("s_waitcnt vmcnt(0)" ::: "memory");
    }
    __builtin_amdgcn_s_barrier();
    __builtin_amdgcn_s_setprio(1);
#pragma unroll
    for (int ks = 0; ks < 2; ks++){
      s8v af[4], bfr[4];
#pragma unroll
      for (int f = 0; f < 4; f++){
        int ch = (((ks * 4 + l4) ^ (l15 & 7)) << 3);
        af[f]  = *reinterpret_cast<const s8v*>(&Asm[cur][(wr * 64 + f * 16 + l15) * 64 + ch]);
        bfr[f] = *reinterpret_cast<const s8v*>(&Bsm[cur][(wc * 64 + f * 16 + l15) * 64 + ch]);
      }
#pragma unroll
      for (int fr = 0; fr < 4; fr++)
#pragma unroll
        for (int fc = 0; fc < 4; fc++)
          acc[fr][fc] = __builtin_amdgcn_mfma_f32_16x16x32_bf16(af[fr], bfr[fc], acc[fr][fc], 0, 0, 0);
    }
    __builtin_amdgcn_s_setprio(0);
    __builtin_amdgcn_s_barrier();
  }
#pragma unroll
  for (int fr = 0; fr < 4; fr++){
    int row = mb + wr * 64 + fr * 16 + l4 * 4;
#pragma unroll
    for (int fc = 0; fc < 4; fc++){
      int col = nb + wc * 64 + fc * 16 + l15;
      float bv = bias[col];
#pragma unroll
      for (int r = 0; r < 4; r++)
        C[(size_t)(row + r) * 1024 + col] = acc[fr][fc][r] + bv;
    }
  }
}

// ---------------- flash attention (split-KV, QBLK=128, swapped QK^T) ----------------
// Grid 1024 = 4 blocks/CU (LDS 40KB): each block does HALF the KV range (16 tiles)
// for one (bh, q-tile), writing partial fp32 O and partial lsum. Fixed-max softmax
// makes the split exactly associative. 4 waves x 32 q-rows; K dbuf, V single-buffer
// (r7 ledger: pre-QK vmcnt(4), pre-PV vmcnt(2), 3 barriers/iter).
__global__ __launch_bounds__(256, 4) void k_flash(
    const ushort_t* __restrict__ Qh, const ushort_t* __restrict__ Kh,
    const ushort_t* __restrict__ Vth, float* __restrict__ Of, float* __restrict__ Lf){
  __shared__ __align__(16) ushort_t KhS[2][64 * 64];
  __shared__ __align__(16) ushort_t VhS[64 * 64];
  __shared__ __align__(16) ushort_t PhS[128 * 64];
  const int lid = blockIdx.x;             // 0..1023
  const int xcd = lid & 7, g = lid >> 3;  // 8 XCDs x 128 blocks
  const int bh = xcd * 4 + (g & 3);       // each XCD owns 4 heads (K/V L2-resident)
  const int qs = g >> 2;                  // 0..31
  const int qb = (qs & 15) * 128;
  const int sp = qs >> 4;                 // KV split 0/1
  const int kt0 = sp * 16;
  const int tid = threadIdx.x, wave = tid >> 6, lane = tid & 63;
  const int l15 = lane & 15, l4 = lane >> 4;
  const size_t hbase = (size_t)bh * SEQ * 64;
  const int rsub = lane >> 3;
  const int schunk = ((lane & 7) ^ rsub) * 8;

  // Q fragments (hi only), 32 q-rows per wave (2 fr groups of 16)
  s8v qhf[2][2];
#pragma unroll
  for (int fr = 0; fr < 2; fr++)
#pragma unroll
    for (int ks = 0; ks < 2; ks++){
      size_t off = hbase + (size_t)(qb + wave * 32 + fr * 16 + l15) * 64 + ks * 32 + l4 * 8;
      qhf[fr][ks] = *reinterpret_cast<const s8v*>(&Qh[off]);
    }

  f32x4 o[2][4] = {};
  float lsum[2] = {0.f, 0.f};

  auto stageK = [&](int buf, int kt){
    int kvb = kt * 64;
#pragma unroll
    for (int i = 0; i < 2; i++){
      int row = (i * 4 + wave) * 8 + rsub;
      g2l16(Kh + hbase + (size_t)(kvb + row) * 64 + schunk, &KhS[buf][(i * 4 + wave) * 512]);
    }
  };
  auto stageV = [&](int kt){
    int kvb = kt * 64;
#pragma unroll
    for (int i = 0; i < 2; i++){
      int row = (i * 4 + wave) * 8 + rsub;
      g2l16(Vth + ((size_t)bh * 64 + row) * SEQ + kvb + schunk, &VhS[(i * 4 + wave) * 512]);
    }
  };

  stageK(0, kt0);

  for (int i = 0; i < 16; i++){
    const int kt = kt0 + i;
    const int cur = i & 1;
    stageV(kt);                     // V[kt] lands during QK
    if (i < 15){
      stageK(cur ^ 1, kt + 1);      // K[kt+1] in flight across the whole iter
      asm volatile("s_waitcnt vmcnt(4)" ::: "memory");  // K[kt] landed
    } else {
      asm volatile("s_waitcnt vmcnt(2)" ::: "memory");
    }
    __builtin_amdgcn_s_barrier();

    // S^T = Kh Qh^T (swapped); each kh fragment feeds both fr groups
    f32x4 s[2][4] = {};
    __builtin_amdgcn_s_setprio(1);
#pragma unroll
    for (int ks = 0; ks < 2; ks++)
#pragma unroll
      for (int fc = 0; fc < 4; fc++){
        int rK = fc * 16 + l15;
        int ch = ((ks * 4 + l4) ^ (rK & 7)) << 3;
        s8v kh = *reinterpret_cast<const s8v*>(&KhS[cur][rK * 64 + ch]);
        s[0][fc] = __builtin_amdgcn_mfma_f32_16x16x32_bf16(kh, qhf[0][ks], s[0][fc], 0, 0, 0);
        s[1][fc] = __builtin_amdgcn_mfma_f32_16x16x32_bf16(kh, qhf[1][ks], s[1][fc], 0, 0, 0);
      }
    __builtin_amdgcn_s_setprio(0);

    // fixed-max softmax on S^T: lane holds q = wave*32 + fr*16 + l15,
    // kv = fc*16 + l4*4 + r. Pack to bf16, write chunk-XOR-swizzled b64.
#pragma unroll
    for (int fr = 0; fr < 2; fr++){
      int q = wave * 32 + fr * 16 + l15;
      int key = q & 7;
      int base = q * 64;
#pragma unroll
      for (int fc = 0; fc < 4; fc++){
        float p0 = __builtin_amdgcn_exp2f(s[fr][fc][0] - MFIX);
        float p1 = __builtin_amdgcn_exp2f(s[fr][fc][1] - MFIX);
        float p2 = __builtin_amdgcn_exp2f(s[fr][fc][2] - MFIX);
        float p3 = __builtin_amdgcn_exp2f(s[fr][fc][3] - MFIX);
        lsum[fr] += (p0 + p1) + (p2 + p3);
        uint2 w;
        w.x = cvt_pk_bf16(p0, p1);
        w.y = cvt_pk_bf16(p2, p3);
        *reinterpret_cast<uint2*>(
            &PhS[base + (((2 * fc + (l4 >> 1)) ^ key) << 3) + ((l4 & 1) << 2)]) = w;
      }
    }

    if (i < 15){
      asm volatile("s_waitcnt vmcnt(2)" ::: "memory");  // V[kt] landed (K[kt+1] in flight)
    } else {
      asm volatile("s_waitcnt vmcnt(0)" ::: "memory");
    }
    __builtin_amdgcn_s_barrier();

    // O += P V ; each vh fragment feeds both fr groups
    __builtin_amdgcn_s_setprio(1);
#pragma unroll
    for (int c = 0; c < 2; c++){
      s8v pa[2];
#pragma unroll
      for (int fr = 0; fr < 2; fr++){
        int q = wave * 32 + fr * 16 + l15;
        pa[fr] = *reinterpret_cast<const s8v*>(&PhS[q * 64 + (((c * 4 + l4) ^ (q & 7)) << 3)]);
      }
#pragma unroll
      for (int fd = 0; fd < 4; fd++){
        int rV = fd * 16 + l15;
        int ch = ((c * 4 + l4) ^ (rV & 7)) << 3;
        s8v vh = *reinterpret_cast<const s8v*>(&VhS[rV * 64 + ch]);
        o[0][fd] = __builtin_amdgcn_mfma_f32_16x16x32_bf16(pa[0], vh, o[0][fd], 0, 0, 0);
        o[1][fd] = __builtin_amdgcn_mfma_f32_16x16x32_bf16(pa[1], vh, o[1][fd], 0, 0, 0);
      }
    }
    __builtin_amdgcn_s_setprio(0);
    __builtin_amdgcn_s_barrier();   // all waves done reading VhS + KhS[cur]
  }

  // epilogue: partial fp32 O and lsum for this KV half
  const size_t obase = (size_t)(sp * 32 + bh) * 2048;
#pragma unroll
  for (int fr = 0; fr < 2; fr++){
    lsum[fr] += __shfl_xor(lsum[fr], 16);
    lsum[fr] += __shfl_xor(lsum[fr], 32);
    if (l4 == 0)
      Lf[obase + qb + wave * 32 + fr * 16 + l15] = lsum[fr];
#pragma unroll
    for (int r = 0; r < 4; r++){
      int n = qb + wave * 32 + fr * 16 + l4 * 4 + r;
      size_t rowbase = (obase + n) * 64;
#pragma unroll
      for (int fd = 0; fd < 4; fd++)
        Of[rowbase + fd * 16 + l15] = o[fr][fd][r];
    }
  }
}

// ---------------- split combine: Ah = (O0+O1)/(L0+L1), bf16 ----------------
__global__ __launch_bounds__(256) void k_comb(
    const float* __restrict__ Of, const float* __restrict__ Lf,
    ushort_t* __restrict__ Ah){
  const int bid = blockIdx.x;            // 0..4095
  const int bh = bid >> 7;
  const int idx = (bid & 127) * 256 + threadIdx.x;   // 0..32767
  const int q = idx >> 4;
  const int dd = (idx & 15) << 2;
  const size_t base = ((size_t)bh * 2048 + q) * 64 + dd;
  float4 a0 = *reinterpret_cast<const float4*>(&Of[base]);
  float4 a1 = *reinterpret_cast<const float4*>(&Of[base + (size_t)NBH * 2048 * 64]);
  float L = Lf[(size_t)bh * 2048 + q] + Lf[(size_t)(32 + bh) * 2048 + q];
  float inv = 1.f / L;
  int b = bh >> 4, h = bh & 15;
  size_t orow = ((size_t)(b * 2048 + q)) * 1024 + h * 64 + dd;
  *reinterpret_cast<ushort4*>(&Ah[orow]) =
      make_ushort4(f2bf((a0.x + a1.x) * inv), f2bf((a0.y + a1.y) * inv),
                   f2bf((a0.z + a1.z) * inv), f2bf((a0.w + a1.w) * inv));
}

// ---------------- host launch ----------------
extern "C" void kernel_launch(void* const* d_in, const int* in_sizes, int n_in,
                              void* d_out, int out_size, void* d_ws, size_t ws_size,
                              hipStream_t stream){
  const float* x     = (const float*)d_in[0];
  const float* w_qkv = (const float*)d_in[1];
  const float* w_out = (const float*)d_in[2];
  const float* b_out = (const float*)d_in[3];
  float* out = (float*)d_out;
  char* ws = (char*)d_ws;

  ushort_t* Xh    = (ushort_t*)(ws);                      //  8 MB
  ushort_t* Wqt_h = (ushort_t*)(ws + 8388608);            //  6 MB
  ushort_t* Wot_h = (ushort_t*)(ws + 14680064);           //  2 MB
  ushort_t* Qh    = (ushort_t*)(ws + 16777216);           //  8 MB
  ushort_t* Kh    = (ushort_t*)(ws + 25165824);           //  8 MB
  ushort_t* Vth   = (ushort_t*)(ws + 33554432);           //  8 MB
  ushort_t* Ah    = (ushort_t*)(ws + 41943040);           //  8 MB
  float*    Of    = (float*)(ws + 50331648);              // 32 MB (2 splits)
  float*    Lf    = (float*)(ws + 83886080);              // 512 KB (2 splits)

  // 1. fused prep: x -> Xh; w_qkv -> Wqt_h (T); w_out -> Wot_h (T)
  k_prep<<<5120, 256, 0, stream>>>(x, w_qkv, w_out, Xh, Wqt_h, Wot_h);
  // 2. QKV projection with fused per-head epilogue
  k_gemm_qkv<<<dim3(24, 32), 256, 0, stream>>>(Xh, Wqt_h, Qh, Kh, Vth);
  // 3. attention (split-KV) -> partial Of/Lf
  k_flash<<<1024, 256, 0, stream>>>(Qh, Kh, Vth, Of, Lf);
  // 4. combine splits -> Ah (bf16)
  k_comb<<<4096, 256, 0, stream>>>(Of, Lf, Ah);
  // 5. out = Ah @ Wot + b_out
  k_gemm_out<<<dim3(8, 32), 256, 0, stream>>>(Ah, Wot_h, out, b_out);
}

// Round 11
// 117.992 us; speedup vs baseline: 1.0544x; 1.0544x over previous
//
#include <hip/hip_runtime.h>
#include <hip/hip_bf16.h>
#include <stdint.h>

// ---------------- problem constants ----------------
#define PDIM   1024
#define HEADS  16
#define DHEAD  64
#define BATCH  2
#define SEQ    2048
#define ROWS   (BATCH*SEQ)     // 4096
#define NBH    (BATCH*HEADS)   // 32

typedef __attribute__((ext_vector_type(8))) short s8v;    // 8 x bf16 (4 VGPR)
typedef __attribute__((ext_vector_type(4))) float f32x4;  // MFMA accumulator
typedef unsigned short ushort_t;
typedef unsigned int   uint32;

// Q pre-scale: DIM_HEAD^-0.5 * log2(e)  (softmax done in exp2 units)
#define QSCALE 0.18033688011112042f
// fixed softmax bias (log2 units): p = exp2(s - MFIX); cancels in num/denom
#define MFIX 12.0f

// ---------------- helpers ----------------
__device__ __forceinline__ ushort_t f2bf(float x){
  union { float f; uint32 u; } v; v.f = x;
  uint32 r = v.u + 0x7FFFu + ((v.u >> 16) & 1u);   // RTN-even
  return (ushort_t)(r >> 16);
}
__device__ __forceinline__ uint32 cvt_pk_bf16(float lo, float hi){
  uint32 r;
  asm("v_cvt_pk_bf16_f32 %0, %1, %2" : "=v"(r) : "v"(lo), "v"(hi));
  return r;   // bf16(lo) in [15:0], bf16(hi) in [31:16]
}

typedef const __attribute__((address_space(1))) void* gas_ptr;
typedef __attribute__((address_space(3))) void*       las_ptr;
__device__ __forceinline__ void g2l16(const void* g, void* l){
  // dest = wave-uniform LDS base; HW adds lane*16
  __builtin_amdgcn_global_load_lds((gas_ptr)g, (las_ptr)l, 16, 0, 0);
}

// ---------------- fused prep: x cvt + w_qkv tcvt + w_out tcvt ----------------
__global__ __launch_bounds__(256) void k_prep(
    const float* __restrict__ x, const float* __restrict__ w_qkv,
    const float* __restrict__ w_out,
    ushort_t* __restrict__ Xh, ushort_t* __restrict__ Wqt_h,
    ushort_t* __restrict__ Wot_h){
  __shared__ float tile[64][65];
  const int bid = blockIdx.x;
  if (bid < 4096){
    int i = bid * 256 + threadIdx.x;
    float4 v = reinterpret_cast<const float4*>(x)[i];
    reinterpret_cast<ushort4*>(Xh)[i] =
        make_ushort4(f2bf(v.x), f2bf(v.y), f2bf(v.z), f2bf(v.w));
    return;
  }
  const float* src; ushort_t* dst; int R, C, cb, rb;
  if (bid < 4864){
    int t = bid - 4096; src = w_qkv; dst = Wqt_h; R = 1024; C = 3072;
    cb = (t % 48) * 64; rb = (t / 48) * 64;
  } else {
    int t = bid - 4864; src = w_out; dst = Wot_h; R = 1024; C = 1024;
    cb = (t % 16) * 64; rb = (t / 16) * 64;
  }
  int t = threadIdx.x;
  int lw = t >> 6, lc = t & 63;
#pragma unroll
  for (int i = 0; i < 16; i++){
    int r = i * 4 + lw;
    tile[r][lc] = src[(size_t)(rb + r) * C + cb + lc];
  }
  __syncthreads();
#pragma unroll
  for (int i = 0; i < 16; i++){
    int c = i * 4 + lw;
    dst[(size_t)(cb + c) * R + rb + lc] = f2bf(tile[lc][c]);
  }
}

// ---------------- GEMM core (128x128 tile, BK=64, 4 waves, dbuf + swizzle) ----------------
#define GBM 128
#define GBN 128
#define GBK 64

// ---------------- QKV projection GEMM, fused per-head epilogue ----------------
__global__ __launch_bounds__(256, 2) void k_gemm_qkv(
    const ushort_t* __restrict__ Xh, const ushort_t* __restrict__ Wqt_h,
    ushort_t* __restrict__ Qh, ushort_t* __restrict__ Kh, ushort_t* __restrict__ Vth){
  __shared__ __align__(16) ushort_t Asm[2][GBM * GBK];
  __shared__ __align__(16) ushort_t Bsm[2][GBM * GBK];
  const int tid  = threadIdx.x;
  const int wave = tid >> 6, lane = tid & 63;
  const int mb = blockIdx.y * GBM, nb = blockIdx.x * GBN;
  const int wr = wave >> 1, wc = wave & 1;
  const int l15 = lane & 15, l4 = lane >> 4;
  const int rsub = lane >> 3;
  const int schunk = ((lane & 7) ^ rsub) * 8;  // source-swizzled chunk
  f32x4 acc[4][4] = {};

  auto stage = [&](int buf, int kb){
    int k0 = kb * GBK;
#pragma unroll
    for (int i = 0; i < 4; i++){
      int row = (i * 4 + wave) * 8 + rsub;
      g2l16(Xh    + (size_t)(mb + row) * 1024 + k0 + schunk, &Asm[buf][(i * 4 + wave) * 512]);
      g2l16(Wqt_h + (size_t)(nb + row) * 1024 + k0 + schunk, &Bsm[buf][(i * 4 + wave) * 512]);
    }
  };

  stage(0, 0);

  for (int kb = 0; kb < 16; kb++){
    const int cur = kb & 1;
    if (kb < 15){
      stage(cur ^ 1, kb + 1);
      asm volatile("s_waitcnt vmcnt(8)" ::: "memory");
    } else {
      asm volatile("s_waitcnt vmcnt(0)" ::: "memory");
    }
    __builtin_amdgcn_s_barrier();
    __builtin_amdgcn_s_setprio(1);
#pragma unroll
    for (int ks = 0; ks < 2; ks++){
      s8v af[4], bfr[4];
#pragma unroll
      for (int f = 0; f < 4; f++){
        int ch = (((ks * 4 + l4) ^ (l15 & 7)) << 3);
        af[f]  = *reinterpret_cast<const s8v*>(&Asm[cur][(wr * 64 + f * 16 + l15) * 64 + ch]);
        bfr[f] = *reinterpret_cast<const s8v*>(&Bsm[cur][(wc * 64 + f * 16 + l15) * 64 + ch]);
      }
#pragma unroll
      for (int fr = 0; fr < 4; fr++)
#pragma unroll
        for (int fc = 0; fc < 4; fc++)
          acc[fr][fc] = __builtin_amdgcn_mfma_f32_16x16x32_bf16(af[fr], bfr[fc], acc[fr][fc], 0, 0, 0);
    }
    __builtin_amdgcn_s_setprio(0);
    __builtin_amdgcn_s_barrier();
  }

  // fused epilogue: cols [nb,nb+128) all in one part (1024 % 128 == 0)
  const int pnum = nb >> 10;
#pragma unroll
  for (int fr = 0; fr < 4; fr++){
    int row  = mb + wr * 64 + fr * 16 + l4 * 4;
    int b    = row >> 11;
    int nseq = row & 2047;
#pragma unroll
    for (int fc = 0; fc < 4; fc++){
      int col = nb + wc * 64 + fc * 16 + l15;
      int rem = col & 1023;
      int h = rem >> 6, d = rem & 63;
      int bh = b * 16 + h;
      if (pnum == 0){          // Q: scale, hi only
        size_t base = ((size_t)bh * SEQ + nseq) * 64 + d;
#pragma unroll
        for (int r = 0; r < 4; r++)
          Qh[base + (size_t)r * 64] = f2bf(acc[fr][fc][r] * QSCALE);
      } else if (pnum == 1){   // K: hi only
        size_t base = ((size_t)bh * SEQ + nseq) * 64 + d;
#pragma unroll
        for (int r = 0; r < 4; r++)
          Kh[base + (size_t)r * 64] = f2bf(acc[fr][fc][r]);
      } else {                 // V: transposed [bh][d][SEQ]
        size_t base = ((size_t)bh * 64 + d) * SEQ + nseq;
        *reinterpret_cast<ushort4*>(&Vth[base]) =
            make_ushort4(f2bf(acc[fr][fc][0]), f2bf(acc[fr][fc][1]),
                         f2bf(acc[fr][fc][2]), f2bf(acc[fr][fc][3]));
      }
    }
  }
}

// ---------------- out-projection GEMM (plain bf16, dbuf + swizzle) ----------------
__global__ __launch_bounds__(256, 2) void k_gemm_out(
    const ushort_t* __restrict__ Ah, const ushort_t* __restrict__ Bth,
    float* __restrict__ C, const float* __restrict__ bias){
  __shared__ __align__(16) ushort_t Asm[2][GBM * GBK];
  __shared__ __align__(16) ushort_t Bsm[2][GBM * GBK];
  const int tid  = threadIdx.x;
  const int wave = tid >> 6, lane = tid & 63;
  const int mb = blockIdx.y * GBM, nb = blockIdx.x * GBN;
  const int wr = wave >> 1, wc = wave & 1;
  const int l15 = lane & 15, l4 = lane >> 4;
  const int rsub = lane >> 3;
  const int schunk = ((lane & 7) ^ rsub) * 8;
  f32x4 acc[4][4] = {};

  auto stage = [&](int buf, int kb){
    int k0 = kb * GBK;
#pragma unroll
    for (int i = 0; i < 4; i++){
      int row = (i * 4 + wave) * 8 + rsub;
      g2l16(Ah  + (size_t)(mb + row) * 1024 + k0 + schunk, &Asm[buf][(i * 4 + wave) * 512]);
      g2l16(Bth + (size_t)(nb + row) * 1024 + k0 + schunk, &Bsm[buf][(i * 4 + wave) * 512]);
    }
  };

  stage(0, 0);

  for (int kb = 0; kb < 16; kb++){
    const int cur = kb & 1;
    if (kb < 15){
      stage(cur ^ 1, kb + 1);
      asm volatile("s_waitcnt vmcnt(8)" ::: "memory");
    } else {
      asm volatile("s_waitcnt vmcnt(0)" ::: "memory");
    }
    __builtin_amdgcn_s_barrier();
    __builtin_amdgcn_s_setprio(1);
#pragma unroll
    for (int ks = 0; ks < 2; ks++){
      s8v af[4], bfr[4];
#pragma unroll
      for (int f = 0; f < 4; f++){
        int ch = (((ks * 4 + l4) ^ (l15 & 7)) << 3);
        af[f]  = *reinterpret_cast<const s8v*>(&Asm[cur][(wr * 64 + f * 16 + l15) * 64 + ch]);
        bfr[f] = *reinterpret_cast<const s8v*>(&Bsm[cur][(wc * 64 + f * 16 + l15) * 64 + ch]);
      }
#pragma unroll
      for (int fr = 0; fr < 4; fr++)
#pragma unroll
        for (int fc = 0; fc < 4; fc++)
          acc[fr][fc] = __builtin_amdgcn_mfma_f32_16x16x32_bf16(af[fr], bfr[fc], acc[fr][fc], 0, 0, 0);
    }
    __builtin_amdgcn_s_setprio(0);
    __builtin_amdgcn_s_barrier();
  }
#pragma unroll
  for (int fr = 0; fr < 4; fr++){
    int row = mb + wr * 64 + fr * 16 + l4 * 4;
#pragma unroll
    for (int fc = 0; fc < 4; fc++){
      int col = nb + wc * 64 + fc * 16 + l15;
      float bv = bias[col];
#pragma unroll
      for (int r = 0; r < 4; r++)
        C[(size_t)(row + r) * 1024 + col] = acc[fr][fc][r] + bv;
    }
  }
}

// ---------------- flash attention (QBLK=128, KVBLK=128, hoisted addresses) ----------------
// Grid 512 = 2 blocks/CU (LDS 64KB: K 16 + V 16 + P 32). 4 waves x 32 q-rows.
// 16 iterations of 128-kv tiles (half the barriers/waits of KVBLK=64).
// K,V single-buffered: stageK(i+1) issued after QK-done barrier (flies under PV);
// stageV(i+1) issued after PV barrier (flies under next QK). L2-resident => ~300cy.
// All LDS addresses hoisted: koff[2] (+fc*2048B imm), voff[4] (+fd*4096B imm),
// pwoff[8], proff[4] (+fr*4096B imm) -> zero swizzle VALU in the loop.
__global__ __launch_bounds__(256, 2) void k_flash(
    const ushort_t* __restrict__ Qh, const ushort_t* __restrict__ Kh,
    const ushort_t* __restrict__ Vth, ushort_t* __restrict__ Ah){
  __shared__ __align__(16) ushort_t KhS[128 * 64];   // [kv][d]
  __shared__ __align__(16) ushort_t VhS[64 * 128];   // [d][kv]
  __shared__ __align__(16) ushort_t PhS[128 * 128];  // [q][kv]
  const int lid = blockIdx.x;             // 0..511
  const int xcd = lid & 7, g = lid >> 3;  // 8 XCDs x 64 blocks
  const int bh = xcd * 4 + (g & 3);       // each XCD owns 4 heads (K/V L2-resident)
  const int qb = (g >> 2) * 128;
  const int tid = threadIdx.x, wave = tid >> 6, lane = tid & 63;
  const int l15 = lane & 15, l4 = lane >> 4;
  const int b = bh >> 4, h = bh & 15;
  const size_t hbase = (size_t)bh * SEQ * 64;
  const int rsub = lane >> 3;
  const int schunkK = ((lane & 7) ^ rsub) * 8;                       // K stage swizzle
  const int schunkV = ((lane & 15) ^ (wave * 4 + (lane >> 4))) * 8;  // V stage swizzle

  // hoisted LDS offsets (elements); swizzle keys are fc/fd/fr-invariant
  int koff[2], voff[4], proff[4], pwoff[8];
#pragma unroll
  for (int ks = 0; ks < 2; ks++)
    koff[ks] = l15 * 64 + (((ks * 4 + l4) ^ (l15 & 7)) << 3);
#pragma unroll
  for (int c = 0; c < 4; c++){
    voff[c]  = l15 * 128 + (((c * 4 + l4) ^ l15) << 3);
    proff[c] = (wave * 32 + l15) * 128 + (((c * 4 + l4) ^ l15) << 3);
  }
#pragma unroll
  for (int fc = 0; fc < 8; fc++)
    pwoff[fc] = (wave * 32 + l15) * 128 + (((fc * 2 + (l4 >> 1)) ^ l15) << 3) + ((l4 & 1) << 2);

  // Q fragments (hi only), 32 q-rows per wave (2 fr groups of 16)
  s8v qhf[2][2];
#pragma unroll
  for (int fr = 0; fr < 2; fr++)
#pragma unroll
    for (int ks = 0; ks < 2; ks++){
      size_t off = hbase + (size_t)(qb + wave * 32 + fr * 16 + l15) * 64 + ks * 32 + l4 * 8;
      qhf[fr][ks] = *reinterpret_cast<const s8v*>(&Qh[off]);
    }

  f32x4 o[2][4] = {};
  float lsum[2] = {0.f, 0.f};

  auto stageK = [&](int kt){         // 128 rows x 64 d, 4 calls/wave
    int kvb = kt * 128;
#pragma unroll
    for (int i = 0; i < 4; i++){
      int row = (i * 4 + wave) * 8 + rsub;
      g2l16(Kh + hbase + (size_t)(kvb + row) * 64 + schunkK, &KhS[(i * 4 + wave) * 512]);
    }
  };
  auto stageV = [&](int kt){         // 64 rows(d) x 128 kv, 4 calls/wave
    int kvb = kt * 128;
#pragma unroll
    for (int i = 0; i < 4; i++){
      int d = (i * 4 + wave) * 4 + (lane >> 4);
      g2l16(Vth + ((size_t)bh * 64 + d) * SEQ + kvb + schunkV, &VhS[(i * 4 + wave) * 512]);
    }
  };

  stageK(0);
  stageV(0);

  for (int i = 0; i < 16; i++){
    // wait K_i landed (V_i still outstanding: 4)
    if (i < 15) asm volatile("s_waitcnt vmcnt(4)" ::: "memory");
    else        asm volatile("s_waitcnt vmcnt(4)" ::: "memory");
    __builtin_amdgcn_s_barrier();

    // ---- QK phase: S^T = Kh Qh^T, per-fc fused softmax ----
    __builtin_amdgcn_s_setprio(1);
#pragma unroll
    for (int fc = 0; fc < 8; fc++){
      s8v kh0 = *reinterpret_cast<const s8v*>(&KhS[koff[0] + fc * 1024]);
      s8v kh1 = *reinterpret_cast<const s8v*>(&KhS[koff[1] + fc * 1024]);
      f32x4 t0 = {}, t1 = {};
      t0 = __builtin_amdgcn_mfma_f32_16x16x32_bf16(kh0, qhf[0][0], t0, 0, 0, 0);
      t0 = __builtin_amdgcn_mfma_f32_16x16x32_bf16(kh1, qhf[0][1], t0, 0, 0, 0);
      t1 = __builtin_amdgcn_mfma_f32_16x16x32_bf16(kh0, qhf[1][0], t1, 0, 0, 0);
      t1 = __builtin_amdgcn_mfma_f32_16x16x32_bf16(kh1, qhf[1][1], t1, 0, 0, 0);
      {
        float p0 = __builtin_amdgcn_exp2f(t0[0] - MFIX);
        float p1 = __builtin_amdgcn_exp2f(t0[1] - MFIX);
        float p2 = __builtin_amdgcn_exp2f(t0[2] - MFIX);
        float p3 = __builtin_amdgcn_exp2f(t0[3] - MFIX);
        lsum[0] += (p0 + p1) + (p2 + p3);
        uint2 w; w.x = cvt_pk_bf16(p0, p1); w.y = cvt_pk_bf16(p2, p3);
        *reinterpret_cast<uint2*>(&PhS[pwoff[fc]]) = w;
      }
      {
        float p0 = __builtin_amdgcn_exp2f(t1[0] - MFIX);
        float p1 = __builtin_amdgcn_exp2f(t1[1] - MFIX);
        float p2 = __builtin_amdgcn_exp2f(t1[2] - MFIX);
        float p3 = __builtin_amdgcn_exp2f(t1[3] - MFIX);
        lsum[1] += (p0 + p1) + (p2 + p3);
        uint2 w; w.x = cvt_pk_bf16(p0, p1); w.y = cvt_pk_bf16(p2, p3);
        *reinterpret_cast<uint2*>(&PhS[pwoff[fc] + 2048]) = w;
      }
    }
    __builtin_amdgcn_s_setprio(0);

    // V_i landed; all waves done reading KhS
    asm volatile("s_waitcnt vmcnt(0)" ::: "memory");
    __builtin_amdgcn_s_barrier();

    if (i < 15) stageK(i + 1);     // flies under PV

    // ---- PV phase: O += P V ----
    __builtin_amdgcn_s_setprio(1);
#pragma unroll
    for (int c = 0; c < 4; c++){
      s8v pa0 = *reinterpret_cast<const s8v*>(&PhS[proff[c]]);
      s8v pa1 = *reinterpret_cast<const s8v*>(&PhS[proff[c] + 2048]);
#pragma unroll
      for (int fd = 0; fd < 4; fd++){
        s8v vh = *reinterpret_cast<const s8v*>(&VhS[voff[c] + fd * 2048]);
        o[0][fd] = __builtin_amdgcn_mfma_f32_16x16x32_bf16(pa0, vh, o[0][fd], 0, 0, 0);
        o[1][fd] = __builtin_amdgcn_mfma_f32_16x16x32_bf16(pa1, vh, o[1][fd], 0, 0, 0);
      }
    }
    __builtin_amdgcn_s_setprio(0);
    __builtin_amdgcn_s_barrier();   // all waves done reading VhS

    if (i < 15) stageV(i + 1);     // flies under next QK
  }

  // epilogue: lane holds lsum for q=l15 (per fr); reduce l4-groups, then
  // fetch per-output-row sums via lane shuffle. Output row q' = l4*4 + r.
#pragma unroll
  for (int fr = 0; fr < 2; fr++){
    lsum[fr] += __shfl_xor(lsum[fr], 16);
    lsum[fr] += __shfl_xor(lsum[fr], 32);
#pragma unroll
    for (int r = 0; r < 4; r++){
      float inv = 1.f / __shfl(lsum[fr], l4 * 4 + r);
      int n = qb + wave * 32 + fr * 16 + l4 * 4 + r;
      size_t rowbase = (size_t)(b * SEQ + n) * 1024 + h * 64;
#pragma unroll
      for (int fd = 0; fd < 4; fd++)
        Ah[rowbase + fd * 16 + l15] = f2bf(o[fr][fd][r] * inv);
    }
  }
}

// ---------------- host launch ----------------
extern "C" void kernel_launch(void* const* d_in, const int* in_sizes, int n_in,
                              void* d_out, int out_size, void* d_ws, size_t ws_size,
                              hipStream_t stream){
  const float* x     = (const float*)d_in[0];
  const float* w_qkv = (const float*)d_in[1];
  const float* w_out = (const float*)d_in[2];
  const float* b_out = (const float*)d_in[3];
  float* out = (float*)d_out;
  char* ws = (char*)d_ws;

  ushort_t* Xh    = (ushort_t*)(ws);                      //  8 MB
  ushort_t* Wqt_h = (ushort_t*)(ws + 8388608);            //  6 MB
  ushort_t* Wot_h = (ushort_t*)(ws + 14680064);           //  2 MB
  ushort_t* Qh    = (ushort_t*)(ws + 16777216);           //  8 MB
  ushort_t* Kh    = (ushort_t*)(ws + 25165824);           //  8 MB
  ushort_t* Vth   = (ushort_t*)(ws + 33554432);           //  8 MB
  ushort_t* Ah    = (ushort_t*)(ws + 41943040);           //  8 MB

  // 1. fused prep: x -> Xh; w_qkv -> Wqt_h (T); w_out -> Wot_h (T)
  k_prep<<<5120, 256, 0, stream>>>(x, w_qkv, w_out, Xh, Wqt_h, Wot_h);
  // 2. QKV projection with fused per-head epilogue
  k_gemm_qkv<<<dim3(24, 32), 256, 0, stream>>>(Xh, Wqt_h, Qh, Kh, Vth);
  // 3. attention -> Ah (bf16)
  k_flash<<<512, 256, 0, stream>>>(Qh, Kh, Vth, Ah);
  // 4. out = Ah @ Wot + b_out
  k_gemm_out<<<dim3(8, 32), 256, 0, stream>>>(Ah, Wot_h, out, b_out);
}

// Round 12
// 115.704 us; speedup vs baseline: 1.0752x; 1.0198x over previous
//
#include <hip/hip_runtime.h>
#include <hip/hip_bf16.h>
#include <stdint.h>

// ---------------- problem constants ----------------
#define PDIM   1024
#define HEADS  16
#define DHEAD  64
#define BATCH  2
#define SEQ    2048
#define ROWS   (BATCH*SEQ)     // 4096
#define NBH    (BATCH*HEADS)   // 32

typedef __attribute__((ext_vector_type(8))) short s8v;     // 8 x bf16 (4 VGPR)
typedef __attribute__((ext_vector_type(4))) float f32x4;   // 16x16 MFMA accum
typedef __attribute__((ext_vector_type(16))) float f32x16; // 32x32 MFMA accum
typedef unsigned short ushort_t;
typedef unsigned int   uint32;

// Q pre-scale: DIM_HEAD^-0.5 * log2(e)  (softmax done in exp2 units)
#define QSCALE 0.18033688011112042f
// fixed softmax bias (log2 units): p = exp2(s - MFIX); cancels in num/denom
#define MFIX 12.0f

// ---------------- helpers ----------------
__device__ __forceinline__ ushort_t f2bf(float x){
  union { float f; uint32 u; } v; v.f = x;
  uint32 r = v.u + 0x7FFFu + ((v.u >> 16) & 1u);   // RTN-even
  return (ushort_t)(r >> 16);
}
__device__ __forceinline__ uint32 cvt_pk_bf16(float lo, float hi){
  uint32 r;
  asm("v_cvt_pk_bf16_f32 %0, %1, %2" : "=v"(r) : "v"(lo), "v"(hi));
  return r;   // bf16(lo) in [15:0], bf16(hi) in [31:16]
}

typedef const __attribute__((address_space(1))) void* gas_ptr;
typedef __attribute__((address_space(3))) void*       las_ptr;
__device__ __forceinline__ void g2l16(const void* g, void* l){
  // dest = wave-uniform LDS base; HW adds lane*16
  __builtin_amdgcn_global_load_lds((gas_ptr)g, (las_ptr)l, 16, 0, 0);
}

// ---------------- fused prep: x cvt + w_qkv tcvt + w_out tcvt ----------------
__global__ __launch_bounds__(256) void k_prep(
    const float* __restrict__ x, const float* __restrict__ w_qkv,
    const float* __restrict__ w_out,
    ushort_t* __restrict__ Xh, ushort_t* __restrict__ Wqt_h,
    ushort_t* __restrict__ Wot_h){
  __shared__ float tile[64][65];
  const int bid = blockIdx.x;
  if (bid < 4096){
    int i = bid * 256 + threadIdx.x;
    float4 v = reinterpret_cast<const float4*>(x)[i];
    reinterpret_cast<ushort4*>(Xh)[i] =
        make_ushort4(f2bf(v.x), f2bf(v.y), f2bf(v.z), f2bf(v.w));
    return;
  }
  const float* src; ushort_t* dst; int R, C, cb, rb;
  if (bid < 4864){
    int t = bid - 4096; src = w_qkv; dst = Wqt_h; R = 1024; C = 3072;
    cb = (t % 48) * 64; rb = (t / 48) * 64;
  } else {
    int t = bid - 4864; src = w_out; dst = Wot_h; R = 1024; C = 1024;
    cb = (t % 16) * 64; rb = (t / 16) * 64;
  }
  int t = threadIdx.x;
  int lw = t >> 6, lc = t & 63;
#pragma unroll
  for (int i = 0; i < 16; i++){
    int r = i * 4 + lw;
    tile[r][lc] = src[(size_t)(rb + r) * C + cb + lc];
  }
  __syncthreads();
#pragma unroll
  for (int i = 0; i < 16; i++){
    int c = i * 4 + lw;
    dst[(size_t)(cb + c) * R + rb + lc] = f2bf(tile[lc][c]);
  }
}

// ---------------- GEMM core (128x128 tile, BK=64, 4 waves, dbuf + swizzle) ----------------
#define GBM 128
#define GBN 128
#define GBK 64

// ---------------- QKV projection GEMM, fused per-head epilogue ----------------
__global__ __launch_bounds__(256, 2) void k_gemm_qkv(
    const ushort_t* __restrict__ Xh, const ushort_t* __restrict__ Wqt_h,
    ushort_t* __restrict__ Qh, ushort_t* __restrict__ Kh, ushort_t* __restrict__ Vth){
  __shared__ __align__(16) ushort_t Asm[2][GBM * GBK];
  __shared__ __align__(16) ushort_t Bsm[2][GBM * GBK];
  const int tid  = threadIdx.x;
  const int wave = tid >> 6, lane = tid & 63;
  const int mb = blockIdx.y * GBM, nb = blockIdx.x * GBN;
  const int wr = wave >> 1, wc = wave & 1;
  const int l15 = lane & 15, l4 = lane >> 4;
  const int rsub = lane >> 3;
  const int schunk = ((lane & 7) ^ rsub) * 8;  // source-swizzled chunk
  f32x4 acc[4][4] = {};

  auto stage = [&](int buf, int kb){
    int k0 = kb * GBK;
#pragma unroll
    for (int i = 0; i < 4; i++){
      int row = (i * 4 + wave) * 8 + rsub;
      g2l16(Xh    + (size_t)(mb + row) * 1024 + k0 + schunk, &Asm[buf][(i * 4 + wave) * 512]);
      g2l16(Wqt_h + (size_t)(nb + row) * 1024 + k0 + schunk, &Bsm[buf][(i * 4 + wave) * 512]);
    }
  };

  stage(0, 0);

  for (int kb = 0; kb < 16; kb++){
    const int cur = kb & 1;
    if (kb < 15){
      stage(cur ^ 1, kb + 1);
      asm volatile("s_waitcnt vmcnt(8)" ::: "memory");
    } else {
      asm volatile("s_waitcnt vmcnt(0)" ::: "memory");
    }
    __builtin_amdgcn_s_barrier();
    __builtin_amdgcn_s_setprio(1);
#pragma unroll
    for (int ks = 0; ks < 2; ks++){
      s8v af[4], bfr[4];
#pragma unroll
      for (int f = 0; f < 4; f++){
        int ch = (((ks * 4 + l4) ^ (l15 & 7)) << 3);
        af[f]  = *reinterpret_cast<const s8v*>(&Asm[cur][(wr * 64 + f * 16 + l15) * 64 + ch]);
        bfr[f] = *reinterpret_cast<const s8v*>(&Bsm[cur][(wc * 64 + f * 16 + l15) * 64 + ch]);
      }
#pragma unroll
      for (int fr = 0; fr < 4; fr++)
#pragma unroll
        for (int fc = 0; fc < 4; fc++)
          acc[fr][fc] = __builtin_amdgcn_mfma_f32_16x16x32_bf16(af[fr], bfr[fc], acc[fr][fc], 0, 0, 0);
    }
    __builtin_amdgcn_s_setprio(0);
    __builtin_amdgcn_s_barrier();
  }

  // fused epilogue: cols [nb,nb+128) all in one part (1024 % 128 == 0)
  const int pnum = nb >> 10;
#pragma unroll
  for (int fr = 0; fr < 4; fr++){
    int row  = mb + wr * 64 + fr * 16 + l4 * 4;
    int b    = row >> 11;
    int nseq = row & 2047;
#pragma unroll
    for (int fc = 0; fc < 4; fc++){
      int col = nb + wc * 64 + fc * 16 + l15;
      int rem = col & 1023;
      int h = rem >> 6, d = rem & 63;
      int bh = b * 16 + h;
      if (pnum == 0){          // Q: scale, hi only
        size_t base = ((size_t)bh * SEQ + nseq) * 64 + d;
#pragma unroll
        for (int r = 0; r < 4; r++)
          Qh[base + (size_t)r * 64] = f2bf(acc[fr][fc][r] * QSCALE);
      } else if (pnum == 1){   // K: hi only
        size_t base = ((size_t)bh * SEQ + nseq) * 64 + d;
#pragma unroll
        for (int r = 0; r < 4; r++)
          Kh[base + (size_t)r * 64] = f2bf(acc[fr][fc][r]);
      } else {                 // V: transposed [bh][d][SEQ]
        size_t base = ((size_t)bh * 64 + d) * SEQ + nseq;
        *reinterpret_cast<ushort4*>(&Vth[base]) =
            make_ushort4(f2bf(acc[fr][fc][0]), f2bf(acc[fr][fc][1]),
                         f2bf(acc[fr][fc][2]), f2bf(acc[fr][fc][3]));
      }
    }
  }
}

// ---------------- out-projection GEMM (plain bf16, dbuf + swizzle) ----------------
__global__ __launch_bounds__(256, 2) void k_gemm_out(
    const ushort_t* __restrict__ Ah, const ushort_t* __restrict__ Bth,
    float* __restrict__ C, const float* __restrict__ bias){
  __shared__ __align__(16) ushort_t Asm[2][GBM * GBK];
  __shared__ __align__(16) ushort_t Bsm[2][GBM * GBK];
  const int tid  = threadIdx.x;
  const int wave = tid >> 6, lane = tid & 63;
  const int mb = blockIdx.y * GBM, nb = blockIdx.x * GBN;
  const int wr = wave >> 1, wc = wave & 1;
  const int l15 = lane & 15, l4 = lane >> 4;
  const int rsub = lane >> 3;
  const int schunk = ((lane & 7) ^ rsub) * 8;
  f32x4 acc[4][4] = {};

  auto stage = [&](int buf, int kb){
    int k0 = kb * GBK;
#pragma unroll
    for (int i = 0; i < 4; i++){
      int row = (i * 4 + wave) * 8 + rsub;
      g2l16(Ah  + (size_t)(mb + row) * 1024 + k0 + schunk, &Asm[buf][(i * 4 + wave) * 512]);
      g2l16(Bth + (size_t)(nb + row) * 1024 + k0 + schunk, &Bsm[buf][(i * 4 + wave) * 512]);
    }
  };

  stage(0, 0);

  for (int kb = 0; kb < 16; kb++){
    const int cur = kb & 1;
    if (kb < 15){
      stage(cur ^ 1, kb + 1);
      asm volatile("s_waitcnt vmcnt(8)" ::: "memory");
    } else {
      asm volatile("s_waitcnt vmcnt(0)" ::: "memory");
    }
    __builtin_amdgcn_s_barrier();
    __builtin_amdgcn_s_setprio(1);
#pragma unroll
    for (int ks = 0; ks < 2; ks++){
      s8v af[4], bfr[4];
#pragma unroll
      for (int f = 0; f < 4; f++){
        int ch = (((ks * 4 + l4) ^ (l15 & 7)) << 3);
        af[f]  = *reinterpret_cast<const s8v*>(&Asm[cur][(wr * 64 + f * 16 + l15) * 64 + ch]);
        bfr[f] = *reinterpret_cast<const s8v*>(&Bsm[cur][(wc * 64 + f * 16 + l15) * 64 + ch]);
      }
#pragma unroll
      for (int fr = 0; fr < 4; fr++)
#pragma unroll
        for (int fc = 0; fc < 4; fc++)
          acc[fr][fc] = __builtin_amdgcn_mfma_f32_16x16x32_bf16(af[fr], bfr[fc], acc[fr][fc], 0, 0, 0);
    }
    __builtin_amdgcn_s_setprio(0);
    __builtin_amdgcn_s_barrier();
  }
#pragma unroll
  for (int fr = 0; fr < 4; fr++){
    int row = mb + wr * 64 + fr * 16 + l4 * 4;
#pragma unroll
    for (int fc = 0; fc < 4; fc++){
      int col = nb + wc * 64 + fc * 16 + l15;
      float bv = bias[col];
#pragma unroll
      for (int r = 0; r < 4; r++)
        C[(size_t)(row + r) * 1024 + col] = acc[fr][fc][r] + bv;
    }
  }
}

// ---------------- flash attention (32x32 MFMA, in-register P via permlane) ----------------
// Grid 512 (XCD-remapped) = 2 blocks/CU, LDS 32KB (K+V dbuf only — NO P buffer).
// 4 waves x 32 q-rows; KV tiles of 64. QK swapped: C[kv][q] = mfma32x32x16(K, Q^T);
// lane (l31=q, hh=lane>>5) holds 32 P values for q across 2 kv-row-blocks.
// PV A-frag (P[q][kv=8hh+j]) assembled IN REGISTERS: cvt_pk pairs + 2x
// v_permlane32_swap per 16-kv step (swap(w0,w2)->frags 0&2, swap(w1,w3)->1&3).
// lsum = per-lane scalar (+1 shfl_xor at end). K/V frag reads chunk-XOR swizzled
// (uniform 8-chunk bank coverage). 2 barriers/iter, counted vmcnt(4).
__global__ __launch_bounds__(256, 2) void k_flash(
    const ushort_t* __restrict__ Qh, const ushort_t* __restrict__ Kh,
    const ushort_t* __restrict__ Vth, ushort_t* __restrict__ Ah){
  __shared__ __align__(16) ushort_t KhS[2][64 * 64];   // [kv][d]
  __shared__ __align__(16) ushort_t VhS[2][64 * 64];   // [d][kv]
  const int lid = blockIdx.x;             // 0..511
  const int xcd = lid & 7, g = lid >> 3;  // 8 XCDs x 64 blocks
  const int bh = xcd * 4 + (g & 3);       // each XCD owns 4 heads (K/V L2-resident)
  const int qb = (g >> 2) * 128;
  const int tid = threadIdx.x, wave = tid >> 6, lane = tid & 63;
  const int l31 = lane & 31, hh = lane >> 5;
  const int b = bh >> 4, hd = bh & 15;
  const size_t hbase = (size_t)bh * SEQ * 64;
  const int rsub = lane >> 3;             // 0..7
  const int schunk = ((lane & 7) ^ rsub) * 8;

  // frag-read element offsets: row l31, chunk (2s+hh) ^ (l31&7)
  int fch[4];
#pragma unroll
  for (int s = 0; s < 4; s++)
    fch[s] = (((2 * s + hh) ^ (l31 & 7)) << 3);
  const int fbase = l31 * 64;

  // Q as B-operand frags: lane(q=l31, hh) holds Q[q][d = 16s + 8hh + 0..7]
  s8v qf[4];
#pragma unroll
  for (int s = 0; s < 4; s++)
    qf[s] = *reinterpret_cast<const s8v*>(
        &Qh[hbase + (size_t)(qb + wave * 32 + l31) * 64 + s * 16 + hh * 8]);

  f32x16 o0 = {}, o1 = {};   // O[q][d-block 0], O[q][d-block 1]
  float lsum = 0.f;

  auto stage = [&](int buf, int kt){
    int kvb = kt * 64;
#pragma unroll
    for (int i = 0; i < 2; i++){
      int row = (i * 4 + wave) * 8 + rsub;
      g2l16(Kh  + hbase + (size_t)(kvb + row) * 64 + schunk, &KhS[buf][(i * 4 + wave) * 512]);
      g2l16(Vth + ((size_t)bh * 64 + row) * SEQ + kvb + schunk, &VhS[buf][(i * 4 + wave) * 512]);
    }
  };

  stage(0, 0);

  for (int kt = 0; kt < 32; kt++){
    const int cur = kt & 1;
    if (kt < 31){
      stage(cur ^ 1, kt + 1);                          // next tile's 4 loads in flight
      asm volatile("s_waitcnt vmcnt(4)" ::: "memory"); // current tile's 4 landed
    } else {
      asm volatile("s_waitcnt vmcnt(0)" ::: "memory");
    }
    __builtin_amdgcn_s_barrier();

    // QK: C[kv][q], two 32-kv row blocks, K-dim = 64 d in 4 steps
    f32x16 s0 = {}, s1 = {};
    __builtin_amdgcn_s_setprio(1);
#pragma unroll
    for (int s = 0; s < 4; s++){
      s8v kf0 = *reinterpret_cast<const s8v*>(&KhS[cur][fbase + fch[s]]);
      s8v kf1 = *reinterpret_cast<const s8v*>(&KhS[cur][fbase + 2048 + fch[s]]);
      s0 = __builtin_amdgcn_mfma_f32_32x32x16_bf16(kf0, qf[s], s0, 0, 0, 0);
      s1 = __builtin_amdgcn_mfma_f32_32x32x16_bf16(kf1, qf[s], s1, 0, 0, 0);
    }
    __builtin_amdgcn_s_setprio(0);

    // fixed-max softmax + pack: w[rb][t] = bf16x2(p[2t], p[2t+1])
    uint32 w[2][8];
#pragma unroll
    for (int t = 0; t < 8; t++){
      float pa = __builtin_amdgcn_exp2f(s0[2 * t]     - MFIX);
      float pb = __builtin_amdgcn_exp2f(s0[2 * t + 1] - MFIX);
      lsum += pa + pb;
      w[0][t] = cvt_pk_bf16(pa, pb);
    }
#pragma unroll
    for (int t = 0; t < 8; t++){
      float pa = __builtin_amdgcn_exp2f(s1[2 * t]     - MFIX);
      float pb = __builtin_amdgcn_exp2f(s1[2 * t + 1] - MFIX);
      lsum += pa + pb;
      w[1][t] = cvt_pk_bf16(pa, pb);
    }

    // PV: O[q][d] += P[32q x 16kv] · V[16kv x 32d]; P frags via permlane swaps
    __builtin_amdgcn_s_setprio(1);
#pragma unroll
    for (int s = 0; s < 4; s++){
      const int rb = s >> 1, u = (s & 1) * 4;
      uint32 m0 = w[rb][u],     m2 = w[rb][u + 2];
      uint32 m1 = w[rb][u + 1], m3 = w[rb][u + 3];
      // after swap: m0 = {lo:own, hi:other's lo}, m2 = {lo:other's hi, hi:own}
      asm("v_permlane32_swap_b32 %0, %1" : "+v"(m0), "+v"(m2));
      asm("v_permlane32_swap_b32 %0, %1" : "+v"(m1), "+v"(m3));
      union { uint32 u4[4]; s8v v; } pf;
      pf.u4[0] = m0; pf.u4[1] = m1; pf.u4[2] = m2; pf.u4[3] = m3;
      s8v vf0 = *reinterpret_cast<const s8v*>(&VhS[cur][fbase + fch[s]]);
      s8v vf1 = *reinterpret_cast<const s8v*>(&VhS[cur][fbase + 2048 + fch[s]]);
      o0 = __builtin_amdgcn_mfma_f32_32x32x16_bf16(pf.v, vf0, o0, 0, 0, 0);
      o1 = __builtin_amdgcn_mfma_f32_32x32x16_bf16(pf.v, vf1, o1, 0, 0, 0);
    }
    __builtin_amdgcn_s_setprio(0);
    __builtin_amdgcn_s_barrier();   // all waves done reading cur buffers
  }

  // epilogue: lane holds lsum-half for q=l31; combine halves, then per-reg shfl
  lsum += __shfl_xor(lsum, 32);
  float linv = 1.f / lsum;
#pragma unroll
  for (int r = 0; r < 16; r++){
    int q = (r & 3) + 8 * (r >> 2) + 4 * hh;
    float sc = __shfl(linv, q);
    int n = qb + wave * 32 + q;
    size_t rowb = (size_t)(b * SEQ + n) * 1024 + hd * 64;
    Ah[rowb + l31]      = f2bf(o0[r] * sc);
    Ah[rowb + 32 + l31] = f2bf(o1[r] * sc);
  }
}

// ---------------- host launch ----------------
extern "C" void kernel_launch(void* const* d_in, const int* in_sizes, int n_in,
                              void* d_out, int out_size, void* d_ws, size_t ws_size,
                              hipStream_t stream){
  const float* x     = (const float*)d_in[0];
  const float* w_qkv = (const float*)d_in[1];
  const float* w_out = (const float*)d_in[2];
  const float* b_out = (const float*)d_in[3];
  float* out = (float*)d_out;
  char* ws = (char*)d_ws;

  ushort_t* Xh    = (ushort_t*)(ws);                      //  8 MB
  ushort_t* Wqt_h = (ushort_t*)(ws + 8388608);            //  6 MB
  ushort_t* Wot_h = (ushort_t*)(ws + 14680064);           //  2 MB
  ushort_t* Qh    = (ushort_t*)(ws + 16777216);           //  8 MB
  ushort_t* Kh    = (ushort_t*)(ws + 25165824);           //  8 MB
  ushort_t* Vth   = (ushort_t*)(ws + 33554432);           //  8 MB
  ushort_t* Ah    = (ushort_t*)(ws + 41943040);           //  8 MB

  // 1. fused prep: x -> Xh; w_qkv -> Wqt_h (T); w_out -> Wot_h (T)
  k_prep<<<5120, 256, 0, stream>>>(x, w_qkv, w_out, Xh, Wqt_h, Wot_h);
  // 2. QKV projection with fused per-head epilogue
  k_gemm_qkv<<<dim3(24, 32), 256, 0, stream>>>(Xh, Wqt_h, Qh, Kh, Vth);
  // 3. attention -> Ah (bf16)
  k_flash<<<512, 256, 0, stream>>>(Qh, Kh, Vth, Ah);
  // 4. out = Ah @ Wot + b_out
  k_gemm_out<<<dim3(8, 32), 256, 0, stream>>>(Ah, Wot_h, out, b_out);
}